// Round 1
// baseline (7692.552 us; speedup 1.0000x reference)
//
#include <hip/hip_runtime.h>
#include <hip/hip_bf16.h>

typedef __attribute__((ext_vector_type(8))) short bf16x8;
typedef __attribute__((ext_vector_type(4))) float f32x4;
typedef unsigned short u16;

__device__ __forceinline__ u16 f2b(float f) {
  __hip_bfloat16 h = __float2bfloat16(f);
  return __builtin_bit_cast(u16, h);
}

// ---------- weight transpose + fp32->bf16 convert: src [K][N] f32 -> dst [N][K] bf16
__global__ __launch_bounds__(256) void wt_kernel(const float* __restrict__ src,
                                                 u16* __restrict__ dst, int K, int N) {
  __shared__ float t[32][33];
  int z = blockIdx.z;
  src += (size_t)z * K * N;
  dst += (size_t)z * K * N;
  int n0 = blockIdx.x * 32, k0 = blockIdx.y * 32;
  int tx = threadIdx.x & 31, ty = threadIdx.x >> 5;
#pragma unroll
  for (int p = 0; p < 4; p++) {
    int k = ty + p * 8;
    t[k][tx] = src[(size_t)(k0 + k) * N + n0 + tx];
  }
  __syncthreads();
#pragma unroll
  for (int p = 0; p < 4; p++) {
    int n = ty + p * 8;
    dst[(size_t)(n0 + n) * K + k0 + tx] = f2b(t[tx][n]);
  }
}

// ---------- LayerNorm fp32 -> bf16, rows of 512, 4 rows/block, 64 lanes/row
__global__ __launch_bounds__(256) void ln_kernel(const float* __restrict__ x,
                                                 const float* __restrict__ gw,
                                                 const float* __restrict__ bw,
                                                 u16* __restrict__ out) {
  int row = blockIdx.x * 4 + (threadIdx.x >> 6);
  int lane = threadIdx.x & 63;
  const float* xr = x + (size_t)row * 512 + lane * 8;
  float4 v0 = *(const float4*)xr;
  float4 v1 = *(const float4*)(xr + 4);
  float s = v0.x + v0.y + v0.z + v0.w + v1.x + v1.y + v1.z + v1.w;
#pragma unroll
  for (int m = 1; m < 64; m <<= 1) s += __shfl_xor(s, m);
  float mean = s * (1.0f / 512.0f);
  float f0 = v0.x - mean, f1 = v0.y - mean, f2 = v0.z - mean, f3 = v0.w - mean;
  float f4 = v1.x - mean, f5 = v1.y - mean, f6 = v1.z - mean, f7 = v1.w - mean;
  float q = f0 * f0 + f1 * f1 + f2 * f2 + f3 * f3 + f4 * f4 + f5 * f5 + f6 * f6 + f7 * f7;
#pragma unroll
  for (int m = 1; m < 64; m <<= 1) q += __shfl_xor(q, m);
  float rs = rsqrtf(q * (1.0f / 512.0f) + 1e-5f);
  const float4 g0 = *(const float4*)(gw + lane * 8);
  const float4 g1 = *(const float4*)(gw + lane * 8 + 4);
  const float4 b0 = *(const float4*)(bw + lane * 8);
  const float4 b1 = *(const float4*)(bw + lane * 8 + 4);
  union { u16 us[8]; uint4 v; } pk;
  pk.us[0] = f2b(f0 * rs * g0.x + b0.x);
  pk.us[1] = f2b(f1 * rs * g0.y + b0.y);
  pk.us[2] = f2b(f2 * rs * g0.z + b0.z);
  pk.us[3] = f2b(f3 * rs * g0.w + b0.w);
  pk.us[4] = f2b(f4 * rs * g1.x + b1.x);
  pk.us[5] = f2b(f5 * rs * g1.y + b1.y);
  pk.us[6] = f2b(f6 * rs * g1.z + b1.z);
  pk.us[7] = f2b(f7 * rs * g1.w + b1.w);
  *(uint4*)(out + (size_t)row * 512 + lane * 8) = pk.v;
}

// ---------- GEMM: C[M=8200,N] = A[M,K]bf16 @ W[N,K]bf16(transposed) (+bias)(+gelu)(+res)
// 128x64 tile, BK=32, 4 waves 2x2, each wave 64x32 = 4x2 MFMA 16x16x32 tiles.
template <int BIAS, int GELU, int RES, int OUTF32>
__global__ __launch_bounds__(256) void gemm_kernel(const u16* __restrict__ A,
                                                   const u16* __restrict__ W,
                                                   const float* __restrict__ bias,
                                                   const float* __restrict__ res,
                                                   void* __restrict__ outp,
                                                   int K, int N) {
  __shared__ __align__(16) u16 As[4096];  // [kc 0..3][m 0..127][8]
  __shared__ __align__(16) u16 Bs[2048];  // [kc 0..3][n 0..63][8]
  const int tid = threadIdx.x;
  const int m0 = blockIdx.y * 128, n0 = blockIdx.x * 64;
  const int lane = tid & 63, wid = tid >> 6;
  const int quad = lane >> 4, l16 = lane & 15;
  const int wm = wid >> 1, wn = wid & 1;
  f32x4 acc[4][2];
#pragma unroll
  for (int r = 0; r < 4; r++)
#pragma unroll
    for (int c = 0; c < 2; c++) acc[r][c] = (f32x4){0.f, 0.f, 0.f, 0.f};
  for (int k0 = 0; k0 < K; k0 += 32) {
    __syncthreads();
#pragma unroll
    for (int p = 0; p < 2; p++) {
      int idx = p * 256 + tid;
      int kc = idx >> 7, mm = idx & 127;
      int row = m0 + mm;
      uint4 v = make_uint4(0, 0, 0, 0);
      if (row < 8200) v = *(const uint4*)(A + (size_t)row * K + k0 + kc * 8);
      *(uint4*)(As + idx * 8) = v;
    }
    {
      int kc = tid >> 6, nn = tid & 63;
      *(uint4*)(Bs + tid * 8) = *(const uint4*)(W + (size_t)(n0 + nn) * K + k0 + kc * 8);
    }
    __syncthreads();
    bf16x8 af[4], bfr[2];
#pragma unroll
    for (int r = 0; r < 4; r++)
      af[r] = *(const bf16x8*)(As + (quad * 128 + wm * 64 + r * 16 + l16) * 8);
#pragma unroll
    for (int c = 0; c < 2; c++)
      bfr[c] = *(const bf16x8*)(Bs + (quad * 64 + wn * 32 + c * 16 + l16) * 8);
#pragma unroll
    for (int r = 0; r < 4; r++)
#pragma unroll
      for (int c = 0; c < 2; c++)
        acc[r][c] = __builtin_amdgcn_mfma_f32_16x16x32_bf16(af[r], bfr[c], acc[r][c], 0, 0, 0);
  }
#pragma unroll
  for (int c = 0; c < 2; c++) {
    int col = n0 + wn * 32 + c * 16 + l16;
    float bv = 0.f;
    if (BIAS) bv = bias[col];
#pragma unroll
    for (int r = 0; r < 4; r++) {
#pragma unroll
      for (int e = 0; e < 4; e++) {
        int row = m0 + wm * 64 + r * 16 + quad * 4 + e;
        if (row < 8200) {
          float v = acc[r][c][e] + bv;
          if (GELU) v = 0.5f * v * (1.0f + erff(v * 0.70710678118654752f));
          if (RES) v += res[(size_t)row * N + col];
          if (OUTF32) ((float*)outp)[(size_t)row * N + col] = v;
          else ((u16*)outp)[(size_t)row * N + col] = f2b(v);
        }
      }
    }
  }
}

// ---------- flash attention: one block = (b,h) x 64 q-rows; K-tiles of 32; online softmax
#define NSEQ 1025
#define ATT_SCALE 0.044194173824159216f  // 512**-0.5 (source scales by dim**-0.5!)

__global__ __launch_bounds__(256) void attn_kernel(const u16* __restrict__ Qp, int ldq,
                                                   const u16* __restrict__ Kp, int ldk,
                                                   const u16* __restrict__ Vp, int ldv,
                                                   u16* __restrict__ Op) {
  __shared__ __align__(16) u16 Qs[64 * 72];   // [qrow][d], pad 72
  __shared__ __align__(16) u16 Ks[32 * 72];   // [key][d], pad 72
  __shared__ __align__(16) u16 Vts[64 * 40];  // [d][key], pad 40
  __shared__ __align__(16) u16 Ps[4 * 16 * 40];  // per-wave [qrow][key], pad 40
  int tid = threadIdx.x, lane = tid & 63, wid = tid >> 6;
  int quad = lane >> 4, l16 = lane & 15;
  int bh = blockIdx.y, bb = bh >> 3, hh = bh & 7;
  int q0 = blockIdx.x * 64;
  const size_t baseq = (size_t)bb * NSEQ * ldq + hh * 64;
  const size_t basek = (size_t)bb * NSEQ * ldk + hh * 64;
  const size_t basev = (size_t)bb * NSEQ * ldv + hh * 64;
#pragma unroll
  for (int p = 0; p < 2; p++) {
    int cid = p * 256 + tid, mm = cid >> 3, ch = cid & 7;
    int i = q0 + mm;
    uint4 v = make_uint4(0, 0, 0, 0);
    if (i < NSEQ) v = *(const uint4*)(Qp + baseq + (size_t)i * ldq + ch * 8);
    *(uint4*)(Qs + mm * 72 + ch * 8) = v;
  }
  __syncthreads();
  const bf16x8 qf0 = *(const bf16x8*)(Qs + (wid * 16 + l16) * 72 + quad * 8);
  const bf16x8 qf1 = *(const bf16x8*)(Qs + (wid * 16 + l16) * 72 + 32 + quad * 8);
  f32x4 o[4];
  float mi[4], li[4];
#pragma unroll
  for (int c = 0; c < 4; c++) o[c] = (f32x4){0.f, 0.f, 0.f, 0.f};
#pragma unroll
  for (int r = 0; r < 4; r++) { mi[r] = -1e30f; li[r] = 0.f; }
  for (int kt = 0; kt < 33; kt++) {
    __syncthreads();
    {
      int nn = tid >> 3, ch = tid & 7, j = kt * 32 + nn;
      uint4 kv = make_uint4(0, 0, 0, 0), vv = make_uint4(0, 0, 0, 0);
      if (j < NSEQ) {
        kv = *(const uint4*)(Kp + basek + (size_t)j * ldk + ch * 8);
        vv = *(const uint4*)(Vp + basev + (size_t)j * ldv + ch * 8);
      }
      *(uint4*)(Ks + nn * 72 + ch * 8) = kv;
      u16* pu = (u16*)&vv;
#pragma unroll
      for (int e = 0; e < 8; e++) Vts[(ch * 8 + e) * 40 + nn] = pu[e];
    }
    __syncthreads();
    f32x4 sc[2];
#pragma unroll
    for (int c = 0; c < 2; c++) {
      const bf16x8 kf0 = *(const bf16x8*)(Ks + (c * 16 + l16) * 72 + quad * 8);
      const bf16x8 kf1 = *(const bf16x8*)(Ks + (c * 16 + l16) * 72 + 32 + quad * 8);
      f32x4 t = (f32x4){0.f, 0.f, 0.f, 0.f};
      t = __builtin_amdgcn_mfma_f32_16x16x32_bf16(qf0, kf0, t, 0, 0, 0);
      t = __builtin_amdgcn_mfma_f32_16x16x32_bf16(qf1, kf1, t, 0, 0, 0);
      sc[c] = t;
    }
#pragma unroll
    for (int c = 0; c < 2; c++) {
      int j = kt * 32 + c * 16 + l16;
      float msk = (j < NSEQ) ? 0.f : -1e30f;
#pragma unroll
      for (int e = 0; e < 4; e++) sc[c][e] = sc[c][e] * ATT_SCALE + msk;
    }
#pragma unroll
    for (int r = 0; r < 4; r++) {
      float t = fmaxf(sc[0][r], sc[1][r]);
      t = fmaxf(t, __shfl_xor(t, 1));
      t = fmaxf(t, __shfl_xor(t, 2));
      t = fmaxf(t, __shfl_xor(t, 4));
      t = fmaxf(t, __shfl_xor(t, 8));
      float mn = fmaxf(mi[r], t);
      float al = __expf(mi[r] - mn);
      float p0 = __expf(sc[0][r] - mn);
      float p1 = __expf(sc[1][r] - mn);
      float su = p0 + p1;
      su += __shfl_xor(su, 1);
      su += __shfl_xor(su, 2);
      su += __shfl_xor(su, 4);
      su += __shfl_xor(su, 8);
      li[r] = li[r] * al + su;
      mi[r] = mn;
#pragma unroll
      for (int c = 0; c < 4; c++) o[c][r] *= al;
      Ps[wid * 640 + (quad * 4 + r) * 40 + l16] = f2b(p0);
      Ps[wid * 640 + (quad * 4 + r) * 40 + 16 + l16] = f2b(p1);
    }
    const bf16x8 pf = *(const bf16x8*)(Ps + wid * 640 + l16 * 40 + quad * 8);
#pragma unroll
    for (int c = 0; c < 4; c++) {
      const bf16x8 vf = *(const bf16x8*)(Vts + (c * 16 + l16) * 40 + quad * 8);
      o[c] = __builtin_amdgcn_mfma_f32_16x16x32_bf16(pf, vf, o[c], 0, 0, 0);
    }
  }
  const size_t baseo = (size_t)bb * NSEQ * 512 + hh * 64;
#pragma unroll
  for (int e = 0; e < 4; e++) {
    int i = q0 + wid * 16 + quad * 4 + e;
    if (i < NSEQ) {
      float inv = 1.0f / li[e];
#pragma unroll
      for (int c = 0; c < 4; c++)
        Op[baseo + (size_t)i * 512 + c * 16 + l16] = f2b(o[c][e] * inv);
    }
  }
}

extern "C" void kernel_launch(void* const* d_in, const int* in_sizes, int n_in,
                              void* d_out, int out_size, void* d_ws, size_t ws_size,
                              hipStream_t stream) {
  (void)in_sizes; (void)n_in; (void)out_size; (void)ws_size;
  auto P = [&](int s, int j) { return (const float*)d_in[2 + s * 17 + j]; };
  // param idx: 0 ln1g,1 ln1b,2 Wqkv,3 Wow,4 Wob,5 ln2g,6 ln2b,7 Wq,8 Wkv,
  //            9 W2ow,10 W2ob,11 ln3g,12 ln3b,13 Wf1,14 bf1,15 Wf2,16 bf2
  char* ws = (char*)d_ws;
  u16* WT = (u16*)ws;
  size_t off = 100663296ull;  // 50,331,648 bf16 weight elems
  float* xA = (float*)(ws + off); off += 16793600ull;
  float* xB = (float*)(ws + off); off += 16793600ull;
  float* xA2 = (float*)(ws + off); off += 16793600ull;
  u16* hQ = (u16*)(ws + off); off += 8396800ull;
  u16* hK = (u16*)(ws + off); off += 8396800ull;
  u16* qkv = (u16*)(ws + off); off += 25190400ull;
  u16* attb = (u16*)(ws + off); off += 8396800ull;
  u16* mid = (u16*)(ws + off); off += 33587200ull;

  const int wk[7] = {512, 512, 512, 512, 512, 512, 2048};
  const int wn[7] = {1536, 512, 512, 1024, 512, 2048, 512};
  const int wi[7] = {2, 3, 7, 8, 9, 13, 15};  // Wqkv,Wow,Wq,Wkv,W2ow,Wf1,Wf2
  size_t wtoff[2][7];
  {
    size_t a = 0;
    for (int s = 0; s < 2; s++)
      for (int t = 0; t < 7; t++) { wtoff[s][t] = a; a += (size_t)6 * wk[t] * wn[t]; }
  }
  for (int s = 0; s < 2; s++)
    for (int t = 0; t < 7; t++)
      wt_kernel<<<dim3(wn[t] / 32, wk[t] / 32, 6), 256, 0, stream>>>(
          P(s, wi[t]), WT + wtoff[s][t], wk[t], wn[t]);

  hipMemcpyAsync(xA, d_in[0], 16793600ull, hipMemcpyDeviceToDevice, stream);
  hipMemcpyAsync(xB, d_in[1], 16793600ull, hipMemcpyDeviceToDevice, stream);

  auto lnL = [&](const float* xp, const float* gp, const float* bp, u16* op) {
    ln_kernel<<<2050, 256, 0, stream>>>(xp, gp, bp, op);
  };
  auto gemm_nb = [&](const u16* Ap, const u16* Wp, int K, int N, u16* Op) {
    gemm_kernel<0, 0, 0, 0><<<dim3(N / 64, 65), 256, 0, stream>>>(Ap, Wp, nullptr, nullptr, Op, K, N);
  };
  auto gemm_br = [&](const u16* Ap, const u16* Wp, int K, int N, const float* bp,
                     const float* rp, float* Op) {
    gemm_kernel<1, 0, 1, 1><<<dim3(N / 64, 65), 256, 0, stream>>>(Ap, Wp, bp, rp, Op, K, N);
  };
  auto gemm_bg = [&](const u16* Ap, const u16* Wp, int K, int N, const float* bp, u16* Op) {
    gemm_kernel<1, 1, 0, 0><<<dim3(N / 64, 65), 256, 0, stream>>>(Ap, Wp, bp, nullptr, Op, K, N);
  };
  auto attnL = [&](const u16* q, int ldq, const u16* k, int ldk, const u16* v, int ldv, u16* op) {
    attn_kernel<<<dim3(17, 64), 256, 0, stream>>>(q, ldq, k, ldk, v, ldv, op);
  };

  u16* qb = qkv;
  u16* kvb = qkv + (size_t)8200 * 512;

  for (int i = 0; i < 6; i++) {
    // ---- self-attention, both streams
    for (int s = 0; s < 2; s++) {
      float* x = s ? xB : xA;
      lnL(x, P(s, 0) + i * 512, P(s, 1) + i * 512, hQ);
      gemm_nb(hQ, WT + wtoff[s][0] + (size_t)i * 512 * 1536, 512, 1536, qkv);
      attnL(qkv, 1536, qkv + 512, 1536, qkv + 1024, 1536, attb);
      gemm_br(attb, WT + wtoff[s][1] + (size_t)i * 512 * 512, 512, 512,
              P(s, 4) + i * 512, x, x);
    }
    // ---- cross-attention A: q from xA, kv from xB (A's ln2 for BOTH), out -> xA2
    lnL(xA, P(0, 5) + i * 512, P(0, 6) + i * 512, hQ);
    lnL(xB, P(0, 5) + i * 512, P(0, 6) + i * 512, hK);
    gemm_nb(hQ, WT + wtoff[0][2] + (size_t)i * 512 * 512, 512, 512, qb);
    gemm_nb(hK, WT + wtoff[0][3] + (size_t)i * 512 * 1024, 512, 1024, kvb);
    attnL(qb, 512, kvb, 1024, kvb + 512, 1024, attb);
    gemm_br(attb, WT + wtoff[0][4] + (size_t)i * 512 * 512, 512, 512,
            P(0, 10) + i * 512, xA, xA2);
    // ---- cross-attention B: q from xB, kv from post-self-attn xA (NOT xA2); in-place xB
    lnL(xB, P(1, 5) + i * 512, P(1, 6) + i * 512, hQ);
    lnL(xA, P(1, 5) + i * 512, P(1, 6) + i * 512, hK);
    gemm_nb(hQ, WT + wtoff[1][2] + (size_t)i * 512 * 512, 512, 512, qb);
    gemm_nb(hK, WT + wtoff[1][3] + (size_t)i * 512 * 1024, 512, 1024, kvb);
    attnL(qb, 512, kvb, 1024, kvb + 512, 1024, attb);
    gemm_br(attb, WT + wtoff[1][4] + (size_t)i * 512 * 512, 512, 512,
            P(1, 10) + i * 512, xB, xB);
    // ---- feed-forward A (input/residual xA2), out -> xA (or d_out at last layer)
    float* outA = (i == 5) ? (float*)d_out : xA;
    lnL(xA2, P(0, 11) + i * 512, P(0, 12) + i * 512, hQ);
    gemm_bg(hQ, WT + wtoff[0][5] + (size_t)i * 512 * 2048, 512, 2048, P(0, 14) + i * 2048, mid);
    gemm_br(mid, WT + wtoff[0][6] + (size_t)i * 2048 * 512, 2048, 512,
            P(0, 16) + i * 512, xA2, outA);
    // ---- feed-forward B (input/residual xB), in place (or d_out+offset at last layer)
    float* outB = (i == 5) ? ((float*)d_out + 4198400) : xB;
    lnL(xB, P(1, 11) + i * 512, P(1, 12) + i * 512, hQ);
    gemm_bg(hQ, WT + wtoff[1][5] + (size_t)i * 512 * 2048, 512, 2048, P(1, 14) + i * 2048, mid);
    gemm_br(mid, WT + wtoff[1][6] + (size_t)i * 2048 * 512, 2048, 512,
            P(1, 16) + i * 512, xB, outB);
  }
}

// Round 2
// 6691.403 us; speedup vs baseline: 1.1496x; 1.1496x over previous
//
#include <hip/hip_runtime.h>
#include <hip/hip_bf16.h>

typedef __attribute__((ext_vector_type(8))) short bf16x8;
typedef __attribute__((ext_vector_type(4))) float f32x4;
typedef unsigned short u16;

__device__ __forceinline__ u16 f2b(float f) {
  __hip_bfloat16 h = __float2bfloat16(f);
  return __builtin_bit_cast(u16, h);
}

// ---------- weight transpose + fp32->bf16 convert: src [K][N] f32 -> dst [N][K] bf16
__global__ __launch_bounds__(256) void wt_kernel(const float* __restrict__ src,
                                                 u16* __restrict__ dst, int K, int N) {
  __shared__ float t[32][33];
  int z = blockIdx.z;
  src += (size_t)z * K * N;
  dst += (size_t)z * K * N;
  int n0 = blockIdx.x * 32, k0 = blockIdx.y * 32;
  int tx = threadIdx.x & 31, ty = threadIdx.x >> 5;
#pragma unroll
  for (int p = 0; p < 4; p++) {
    int k = ty + p * 8;
    t[k][tx] = src[(size_t)(k0 + k) * N + n0 + tx];
  }
  __syncthreads();
#pragma unroll
  for (int p = 0; p < 4; p++) {
    int n = ty + p * 8;
    dst[(size_t)(n0 + n) * K + k0 + tx] = f2b(t[tx][n]);
  }
}

// ---------- LayerNorm fp32 -> bf16, rows of 512, 4 rows/block, 64 lanes/row
__global__ __launch_bounds__(256) void ln_kernel(const float* __restrict__ x,
                                                 const float* __restrict__ gw,
                                                 const float* __restrict__ bw,
                                                 u16* __restrict__ out) {
  int row = blockIdx.x * 4 + (threadIdx.x >> 6);
  int lane = threadIdx.x & 63;
  const float* xr = x + (size_t)row * 512 + lane * 8;
  float4 v0 = *(const float4*)xr;
  float4 v1 = *(const float4*)(xr + 4);
  float s = v0.x + v0.y + v0.z + v0.w + v1.x + v1.y + v1.z + v1.w;
#pragma unroll
  for (int m = 1; m < 64; m <<= 1) s += __shfl_xor(s, m);
  float mean = s * (1.0f / 512.0f);
  float f0 = v0.x - mean, f1 = v0.y - mean, f2 = v0.z - mean, f3 = v0.w - mean;
  float f4 = v1.x - mean, f5 = v1.y - mean, f6 = v1.z - mean, f7 = v1.w - mean;
  float q = f0 * f0 + f1 * f1 + f2 * f2 + f3 * f3 + f4 * f4 + f5 * f5 + f6 * f6 + f7 * f7;
#pragma unroll
  for (int m = 1; m < 64; m <<= 1) q += __shfl_xor(q, m);
  float rs = rsqrtf(q * (1.0f / 512.0f) + 1e-5f);
  const float4 g0 = *(const float4*)(gw + lane * 8);
  const float4 g1 = *(const float4*)(gw + lane * 8 + 4);
  const float4 b0 = *(const float4*)(bw + lane * 8);
  const float4 b1 = *(const float4*)(bw + lane * 8 + 4);
  union { u16 us[8]; uint4 v; } pk;
  pk.us[0] = f2b(f0 * rs * g0.x + b0.x);
  pk.us[1] = f2b(f1 * rs * g0.y + b0.y);
  pk.us[2] = f2b(f2 * rs * g0.z + b0.z);
  pk.us[3] = f2b(f3 * rs * g0.w + b0.w);
  pk.us[4] = f2b(f4 * rs * g1.x + b1.x);
  pk.us[5] = f2b(f5 * rs * g1.y + b1.y);
  pk.us[6] = f2b(f6 * rs * g1.z + b1.z);
  pk.us[7] = f2b(f7 * rs * g1.w + b1.w);
  *(uint4*)(out + (size_t)row * 512 + lane * 8) = pk.v;
}

// ---------- GEMM: C[M=8200,N] = A[M,K]bf16 @ W[N,K]bf16(transposed) (+bias)(+gelu)(+res)
// 128x64 tile, BK=32, 4 waves 2x2.  VT mode: cols >= vstart go transposed to
// vt[bh][dh][1088] (per-head V^T for attention; row = b*1025+i -> (b, i)).
template <int BIAS, int GELU, int RES, int OUTF32, int VTM>
__global__ __launch_bounds__(256) void gemm_kernel(const u16* __restrict__ A,
                                                   const u16* __restrict__ W,
                                                   const float* __restrict__ bias,
                                                   const float* __restrict__ res,
                                                   void* __restrict__ outp,
                                                   int K, int N, int vstart,
                                                   u16* __restrict__ vt) {
  __shared__ __align__(16) u16 As[4096];  // [kc 0..3][m 0..127][8]
  __shared__ __align__(16) u16 Bs[2048];  // [kc 0..3][n 0..63][8]
  const int tid = threadIdx.x;
  const int m0 = blockIdx.y * 128, n0 = blockIdx.x * 64;
  const int lane = tid & 63, wid = tid >> 6;
  const int quad = lane >> 4, l16 = lane & 15;
  const int wm = wid >> 1, wn = wid & 1;
  f32x4 acc[4][2];
#pragma unroll
  for (int r = 0; r < 4; r++)
#pragma unroll
    for (int c = 0; c < 2; c++) acc[r][c] = (f32x4){0.f, 0.f, 0.f, 0.f};
  for (int k0 = 0; k0 < K; k0 += 32) {
    __syncthreads();
#pragma unroll
    for (int p = 0; p < 2; p++) {
      int idx = p * 256 + tid;
      int kc = idx >> 7, mm = idx & 127;
      int row = m0 + mm;
      uint4 v = make_uint4(0, 0, 0, 0);
      if (row < 8200) v = *(const uint4*)(A + (size_t)row * K + k0 + kc * 8);
      *(uint4*)(As + idx * 8) = v;
    }
    {
      int kc = tid >> 6, nn = tid & 63;
      *(uint4*)(Bs + tid * 8) = *(const uint4*)(W + (size_t)(n0 + nn) * K + k0 + kc * 8);
    }
    __syncthreads();
    bf16x8 af[4], bfr[2];
#pragma unroll
    for (int r = 0; r < 4; r++)
      af[r] = *(const bf16x8*)(As + (quad * 128 + wm * 64 + r * 16 + l16) * 8);
#pragma unroll
    for (int c = 0; c < 2; c++)
      bfr[c] = *(const bf16x8*)(Bs + (quad * 64 + wn * 32 + c * 16 + l16) * 8);
#pragma unroll
    for (int r = 0; r < 4; r++)
#pragma unroll
      for (int c = 0; c < 2; c++)
        acc[r][c] = __builtin_amdgcn_mfma_f32_16x16x32_bf16(af[r], bfr[c], acc[r][c], 0, 0, 0);
  }
#pragma unroll
  for (int c = 0; c < 2; c++) {
    int col = n0 + wn * 32 + c * 16 + l16;
    float bv = 0.f;
    if (BIAS) bv = bias[col];
    if (VTM && col >= vstart) {
      int hc = col - vstart;
      int hh = hc >> 6, dh = hc & 63;
#pragma unroll
      for (int r = 0; r < 4; r++) {
#pragma unroll
        for (int e = 0; e < 4; e++) {
          int row = m0 + wm * 64 + r * 16 + quad * 4 + e;
          if (row < 8200) {
            int bb = row / 1025, ii = row - bb * 1025;
            vt[(((size_t)(bb * 8 + hh)) * 64 + dh) * 1088 + ii] = f2b(acc[r][c][e]);
          }
        }
      }
    } else {
#pragma unroll
      for (int r = 0; r < 4; r++) {
#pragma unroll
        for (int e = 0; e < 4; e++) {
          int row = m0 + wm * 64 + r * 16 + quad * 4 + e;
          if (row < 8200) {
            float v = acc[r][c][e] + bv;
            if (GELU) v = 0.5f * v * (1.0f + erff(v * 0.70710678118654752f));
            if (RES) v += res[(size_t)row * N + col];
            if (OUTF32) ((float*)outp)[(size_t)row * N + col] = v;
            else ((u16*)outp)[(size_t)row * N + col] = f2b(v);
          }
        }
      }
    }
  }
}

// ---------- flash attention v2: 64-key tiles, V^T input, reg-prefetch, permuted-K
#define ATT_SCALE 0.044194173824159216f  // 512**-0.5 (source scales by dim**-0.5!)
#define SK 72                            // LDS row stride (u16): 144B, 16B-aligned

__global__ __launch_bounds__(256) void attn_kernel(const u16* __restrict__ Qp, int ldq,
                                                   const u16* __restrict__ Kp, int ldk,
                                                   const u16* __restrict__ VT,
                                                   u16* __restrict__ Op) {
  __shared__ __align__(16) u16 Ks[64 * SK];
  __shared__ __align__(16) u16 Vts[64 * SK];
  __shared__ __align__(16) u16 QP[64 * SK];  // Qs (64 rows), later per-wave Ps slabs
  const int tid = threadIdx.x, lane = tid & 63, wid = tid >> 6;
  const int quad = lane >> 4, l16 = lane & 15;
  // XCD swizzle: q-blocks of the same (b,h) stay on one XCD for K/V L2 locality
  int lin = blockIdx.x;
  int xcd = lin & 7, t = lin >> 3;
  int bh = xcd + 8 * (t / 17);
  int q0 = (t % 17) * 64;
  int bb = bh >> 3, hh = bh & 7;
  const size_t baseq = (size_t)bb * 1025 * ldq + hh * 64;
  const size_t basek = (size_t)bb * 1025 * ldk + hh * 64;
  const u16* vtp = VT + (size_t)bh * 64 * 1088;

  // stage Q + K/V tile 0.  K permuted: LDS row j holds key (j%16)*4 + j/16 so a
  // lane's 4 P values (c=0..3 at score col l16) land contiguous at pos l16*4+c.
#pragma unroll
  for (int p = 0; p < 2; p++) {
    int idx = p * 256 + tid, mm = idx >> 3, ch = idx & 7;
    int i = q0 + mm;
    uint4 v = make_uint4(0, 0, 0, 0);
    if (i < 1025) v = *(const uint4*)(Qp + baseq + (size_t)i * ldq + ch * 8);
    *(uint4*)(QP + mm * SK + ch * 8) = v;
    int g = ((mm & 15) << 2) + (mm >> 4);
    *(uint4*)(Ks + mm * SK + ch * 8) = *(const uint4*)(Kp + basek + (size_t)g * ldk + ch * 8);
    *(uint4*)(Vts + mm * SK + ch * 8) = *(const uint4*)(vtp + (size_t)mm * 1088 + ch * 8);
  }
  __syncthreads();
  const bf16x8 qf0 = *(const bf16x8*)(QP + (wid * 16 + l16) * SK + quad * 8);
  const bf16x8 qf1 = *(const bf16x8*)(QP + (wid * 16 + l16) * SK + 32 + quad * 8);
  __syncthreads();  // all Q frag reads done before Ps overwrites QP
  u16* Ps = QP + wid * 16 * SK;

  f32x4 o[4];
  float mi[4], li[4];
#pragma unroll
  for (int c = 0; c < 4; c++) o[c] = (f32x4){0.f, 0.f, 0.f, 0.f};
#pragma unroll
  for (int r = 0; r < 4; r++) { mi[r] = -1e30f; li[r] = 0.f; }

  for (int kt = 0; kt < 17; kt++) {
    // prefetch next K/V tile into registers (overlaps global latency w/ compute)
    uint4 pk[2], pv[2];
    const bool pre = (kt + 1 < 17);
    if (pre) {
#pragma unroll
      for (int p = 0; p < 2; p++) {
        int idx = p * 256 + tid, mm = idx >> 3, ch = idx & 7;
        int g = (kt + 1) * 64 + ((mm & 15) << 2) + (mm >> 4);
        pk[p] = make_uint4(0, 0, 0, 0);
        if (g < 1025) pk[p] = *(const uint4*)(Kp + basek + (size_t)g * ldk + ch * 8);
        pv[p] = *(const uint4*)(vtp + (size_t)mm * 1088 + (kt + 1) * 64 + ch * 8);
      }
    }
    // QK^T: 16q x 64keys
    f32x4 sc[4];
#pragma unroll
    for (int c = 0; c < 4; c++) {
      const bf16x8 kf0 = *(const bf16x8*)(Ks + (c * 16 + l16) * SK + quad * 8);
      const bf16x8 kf1 = *(const bf16x8*)(Ks + (c * 16 + l16) * SK + 32 + quad * 8);
      f32x4 z = (f32x4){0.f, 0.f, 0.f, 0.f};
      z = __builtin_amdgcn_mfma_f32_16x16x32_bf16(qf0, kf0, z, 0, 0, 0);
      z = __builtin_amdgcn_mfma_f32_16x16x32_bf16(qf1, kf1, z, 0, 0, 0);
      sc[c] = z;
    }
    if (kt == 16) {
#pragma unroll
      for (int c = 0; c < 4; c++) {
        float msk = (l16 == 0 && c == 0) ? 0.f : -1e30f;  // key 1024 only
#pragma unroll
        for (int e = 0; e < 4; e++) sc[c][e] = sc[c][e] * ATT_SCALE + msk;
      }
    } else {
#pragma unroll
      for (int c = 0; c < 4; c++)
#pragma unroll
        for (int e = 0; e < 4; e++) sc[c][e] *= ATT_SCALE;
    }
    // online softmax, one row r per accumulator element
#pragma unroll
    for (int r = 0; r < 4; r++) {
      float m = fmaxf(fmaxf(sc[0][r], sc[1][r]), fmaxf(sc[2][r], sc[3][r]));
      m = fmaxf(m, __shfl_xor(m, 1));
      m = fmaxf(m, __shfl_xor(m, 2));
      m = fmaxf(m, __shfl_xor(m, 4));
      m = fmaxf(m, __shfl_xor(m, 8));
      float mn = fmaxf(mi[r], m);
      float al = __expf(mi[r] - mn);
      float p0 = __expf(sc[0][r] - mn);
      float p1 = __expf(sc[1][r] - mn);
      float p2 = __expf(sc[2][r] - mn);
      float p3 = __expf(sc[3][r] - mn);
      float su = (p0 + p1) + (p2 + p3);
      su += __shfl_xor(su, 1);
      su += __shfl_xor(su, 2);
      su += __shfl_xor(su, 4);
      su += __shfl_xor(su, 8);
      li[r] = li[r] * al + su;
      mi[r] = mn;
      o[0][r] *= al; o[1][r] *= al; o[2][r] *= al; o[3][r] *= al;
      union { u16 q[4]; uint2 d; } pq;
      pq.q[0] = f2b(p0); pq.q[1] = f2b(p1); pq.q[2] = f2b(p2); pq.q[3] = f2b(p3);
      *(uint2*)(Ps + (quad * 4 + r) * SK + l16 * 4) = pq.d;
    }
    // P (A-frag) x V^T (B-frag)
    const bf16x8 pf0 = *(const bf16x8*)(Ps + l16 * SK + quad * 8);
    const bf16x8 pf1 = *(const bf16x8*)(Ps + l16 * SK + 32 + quad * 8);
#pragma unroll
    for (int cd = 0; cd < 4; cd++) {
      const bf16x8 vf0 = *(const bf16x8*)(Vts + (cd * 16 + l16) * SK + quad * 8);
      const bf16x8 vf1 = *(const bf16x8*)(Vts + (cd * 16 + l16) * SK + 32 + quad * 8);
      o[cd] = __builtin_amdgcn_mfma_f32_16x16x32_bf16(pf0, vf0, o[cd], 0, 0, 0);
      o[cd] = __builtin_amdgcn_mfma_f32_16x16x32_bf16(pf1, vf1, o[cd], 0, 0, 0);
    }
    __syncthreads();
    if (pre) {
#pragma unroll
      for (int p = 0; p < 2; p++) {
        int idx = p * 256 + tid, mm = idx >> 3, ch = idx & 7;
        *(uint4*)(Ks + mm * SK + ch * 8) = pk[p];
        *(uint4*)(Vts + mm * SK + ch * 8) = pv[p];
      }
      __syncthreads();
    }
  }
  const size_t baseo = (size_t)bb * 1025 * 512 + hh * 64;
#pragma unroll
  for (int e = 0; e < 4; e++) {
    int i = q0 + wid * 16 + quad * 4 + e;
    if (i < 1025) {
      float inv = 1.0f / li[e];
#pragma unroll
      for (int cd = 0; cd < 4; cd++)
        Op[baseo + (size_t)i * 512 + cd * 16 + l16] = f2b(o[cd][e] * inv);
    }
  }
}

extern "C" void kernel_launch(void* const* d_in, const int* in_sizes, int n_in,
                              void* d_out, int out_size, void* d_ws, size_t ws_size,
                              hipStream_t stream) {
  (void)in_sizes; (void)n_in; (void)out_size; (void)ws_size;
  auto P = [&](int s, int j) { return (const float*)d_in[2 + s * 17 + j]; };
  char* ws = (char*)d_ws;
  u16* WT = (u16*)ws;
  size_t off = 100663296ull;  // 50,331,648 bf16 weight elems
  float* xA = (float*)(ws + off); off += 16793600ull;
  float* xB = (float*)(ws + off); off += 16793600ull;
  float* xA2 = (float*)(ws + off); off += 16793600ull;
  u16* hQ = (u16*)(ws + off); off += 8396800ull;
  u16* hK = (u16*)(ws + off); off += 8396800ull;
  u16* qkv = (u16*)(ws + off); off += 25190400ull;
  u16* attb = (u16*)(ws + off); off += 8396800ull;
  u16* mid = (u16*)(ws + off); off += 33587200ull;  // FF mid; doubles as V^T buf in attn phase

  const int wk[7] = {512, 512, 512, 512, 512, 512, 2048};
  const int wn[7] = {1536, 512, 512, 1024, 512, 2048, 512};
  const int wi[7] = {2, 3, 7, 8, 9, 13, 15};  // Wqkv,Wow,Wq,Wkv,W2ow,Wf1,Wf2
  size_t wtoff[2][7];
  {
    size_t a = 0;
    for (int s = 0; s < 2; s++)
      for (int t = 0; t < 7; t++) { wtoff[s][t] = a; a += (size_t)6 * wk[t] * wn[t]; }
  }
  for (int s = 0; s < 2; s++)
    for (int t = 0; t < 7; t++)
      wt_kernel<<<dim3(wn[t] / 32, wk[t] / 32, 6), 256, 0, stream>>>(
          P(s, wi[t]), WT + wtoff[s][t], wk[t], wn[t]);

  hipMemcpyAsync(xA, d_in[0], 16793600ull, hipMemcpyDeviceToDevice, stream);
  hipMemcpyAsync(xB, d_in[1], 16793600ull, hipMemcpyDeviceToDevice, stream);

  auto lnL = [&](const float* xp, const float* gp, const float* bp, u16* op) {
    ln_kernel<<<2050, 256, 0, stream>>>(xp, gp, bp, op);
  };
  auto gemm_nb = [&](const u16* Ap, const u16* Wp, int K, int N, u16* Op) {
    gemm_kernel<0, 0, 0, 0, 0><<<dim3(N / 64, 65), 256, 0, stream>>>(
        Ap, Wp, nullptr, nullptr, Op, K, N, 0, nullptr);
  };
  auto gemm_nbv = [&](const u16* Ap, const u16* Wp, int K, int N, u16* Op, int vstart) {
    gemm_kernel<0, 0, 0, 0, 1><<<dim3(N / 64, 65), 256, 0, stream>>>(
        Ap, Wp, nullptr, nullptr, Op, K, N, vstart, mid);
  };
  auto gemm_br = [&](const u16* Ap, const u16* Wp, int K, int N, const float* bp,
                     const float* rp, float* Op) {
    gemm_kernel<1, 0, 1, 1, 0><<<dim3(N / 64, 65), 256, 0, stream>>>(
        Ap, Wp, bp, rp, Op, K, N, 0, nullptr);
  };
  auto gemm_bg = [&](const u16* Ap, const u16* Wp, int K, int N, const float* bp, u16* Op) {
    gemm_kernel<1, 1, 0, 0, 0><<<dim3(N / 64, 65), 256, 0, stream>>>(
        Ap, Wp, bp, nullptr, Op, K, N, 0, nullptr);
  };
  auto attnL = [&](const u16* q, int ldq, const u16* k, int ldk, u16* op) {
    attn_kernel<<<1088, 256, 0, stream>>>(q, ldq, k, ldk, mid, op);
  };

  u16* qb = qkv;
  u16* kvb = qkv + (size_t)8200 * 512;

  for (int i = 0; i < 6; i++) {
    // ---- self-attention, both streams (V routed transposed to mid by GEMM)
    for (int s = 0; s < 2; s++) {
      float* x = s ? xB : xA;
      lnL(x, P(s, 0) + i * 512, P(s, 1) + i * 512, hQ);
      gemm_nbv(hQ, WT + wtoff[s][0] + (size_t)i * 512 * 1536, 512, 1536, qkv, 1024);
      attnL(qkv, 1536, qkv + 512, 1536, attb);
      gemm_br(attb, WT + wtoff[s][1] + (size_t)i * 512 * 512, 512, 512,
              P(s, 4) + i * 512, x, x);
    }
    // ---- cross-attention A: q from xA, kv from xB (A's ln2 for BOTH), out -> xA2
    lnL(xA, P(0, 5) + i * 512, P(0, 6) + i * 512, hQ);
    lnL(xB, P(0, 5) + i * 512, P(0, 6) + i * 512, hK);
    gemm_nb(hQ, WT + wtoff[0][2] + (size_t)i * 512 * 512, 512, 512, qb);
    gemm_nbv(hK, WT + wtoff[0][3] + (size_t)i * 512 * 1024, 512, 1024, kvb, 512);
    attnL(qb, 512, kvb, 1024, attb);
    gemm_br(attb, WT + wtoff[0][4] + (size_t)i * 512 * 512, 512, 512,
            P(0, 10) + i * 512, xA, xA2);
    // ---- cross-attention B: q from xB, kv from post-self-attn xA (NOT xA2)
    lnL(xB, P(1, 5) + i * 512, P(1, 6) + i * 512, hQ);
    lnL(xA, P(1, 5) + i * 512, P(1, 6) + i * 512, hK);
    gemm_nb(hQ, WT + wtoff[1][2] + (size_t)i * 512 * 512, 512, 512, qb);
    gemm_nbv(hK, WT + wtoff[1][3] + (size_t)i * 512 * 1024, 512, 1024, kvb, 512);
    attnL(qb, 512, kvb, 1024, attb);
    gemm_br(attb, WT + wtoff[1][4] + (size_t)i * 512 * 512, 512, 512,
            P(1, 10) + i * 512, xB, xB);
    // ---- feed-forward A (input/residual xA2), out -> xA (or d_out at last layer)
    float* outA = (i == 5) ? (float*)d_out : xA;
    lnL(xA2, P(0, 11) + i * 512, P(0, 12) + i * 512, hQ);
    gemm_bg(hQ, WT + wtoff[0][5] + (size_t)i * 512 * 2048, 512, 2048, P(0, 14) + i * 2048, mid);
    gemm_br(mid, WT + wtoff[0][6] + (size_t)i * 2048 * 512, 2048, 512,
            P(0, 16) + i * 512, xA2, outA);
    // ---- feed-forward B (input/residual xB)
    float* outB = (i == 5) ? ((float*)d_out + 4198400) : xB;
    lnL(xB, P(1, 11) + i * 512, P(1, 12) + i * 512, hQ);
    gemm_bg(hQ, WT + wtoff[1][5] + (size_t)i * 512 * 2048, 512, 2048, P(1, 14) + i * 2048, mid);
    gemm_br(mid, WT + wtoff[1][6] + (size_t)i * 2048 * 512, 2048, 512,
            P(1, 16) + i * 512, xB, outB);
  }
}